// Round 7
// baseline (124.788 us; speedup 1.0000x reference)
//
#include <hip/hip_runtime.h>
#include <hip/hip_bf16.h>

// HybridLoss: focal + contrastive + 0.1*graph_reg.  N=8192, D=128.
// v7: synthesis round.  Evidence: v5(2496 WG) == v6(632 WG) == 107.7 total
// => total is floor-dominated (41us poison fill + reset + boundaries) once
// kernels are fast; v1's 3-launch global-prestaged design (102.4) beat all
// self-staging 2-launch variants (107.7) because its pair kernel reads
// perfectly-coalesced pre-swizzled bf16 fragments straight from L2.
// v7 = v1 structure with every since-validated trim:
//  - aux 832->168 WGs; fbf (2MB) and sqn dropped entirely (slow path reads
//    f32 feat directly and derives norms in-reg -- v5-verified).
//  - pair 2080->520 WGs, 4 tiles/block serial; fast-path tile ~0.3us
//    (coalesced L2 reads, 16 MFMA, pure-VALU min; NOT v4's scattered chains).
//  - screen: augmented-row MFMA (A=[-2f0..23,sq24,1,0..], B=[f0..23,1,sq24,
//    0..]; acc IS sq24; wave-min >= 2 => skip), verified v1/v5/v6.
//  - slow path: v5-verbatim scattered-f32 full gram (diag tiles in practice).
//  - same-label pairs closed form; plain distinct-slot stores; no atomics,
//    no fences, no LDS in pair kernel.

#define N_PTS 8192
#define DIM 128

typedef __bf16 bf16x8 __attribute__((ext_vector_type(8)));
typedef float f32x4 __attribute__((ext_vector_type(4)));

// aux grid: [0,64) swizzle, [64,96) colsum, [96,104) focal, [104,168) graph
#define NSWZ 64
#define NCOL 32
#define NFOC 8
#define NGRA 64
#define NAUX (NSWZ + NCOL + NFOC + NGRA)
#define NPAIRB 520           // x4 tiles = 2080 upper-tri 128x128 tiles

// workspace layout (bytes)
#define ASCR_OFF 0                       // __bf16[8192*32] screen A (swizzled)
#define BSCR_OFF 524288                  // __bf16[8192*32] screen B
#define VPART_OFF 1048576                // float[32][256] col sums (cls0 | cls1)
#define SPART_OFF 1081344                // float4[32] : {ssq_all, ssq_cls1, n1, 0}
#define CPART_OFF 1081856                // float[520*4] pair per-wave partials
#define FPART_OFF 1090176                // float[8*4]   focal per-wave partials
#define GPART_OFF 1090304                // float[64*4]  graph per-wave partials

// screen-panel unit(g,q,m) = ((g*4+q)*16+m)*16 bytes; row r=g*16+m holds
// dims 8q..8q+7 (bf16 x8 = 16B).  g = r>>4 global (0..511).
__device__ __forceinline__ int uoff(int g, int q, int m) {
    return ((g * 4 + q) * 16 + m) * 16;
}

__device__ __forceinline__ float ssq4(const float4 a) {
    return a.x * a.x + a.y * a.y + a.z * a.z + a.w * a.w;
}
__device__ __forceinline__ void store8(void* dst, float4 a, float4 b, float sc) {
    union { __bf16 h[8]; uint4 u; } p;
    p.h[0] = (__bf16)(sc * a.x); p.h[1] = (__bf16)(sc * a.y);
    p.h[2] = (__bf16)(sc * a.z); p.h[3] = (__bf16)(sc * a.w);
    p.h[4] = (__bf16)(sc * b.x); p.h[5] = (__bf16)(sc * b.y);
    p.h[6] = (__bf16)(sc * b.z); p.h[7] = (__bf16)(sc * b.w);
    *reinterpret_cast<uint4*>(dst) = p.u;
}
__device__ __forceinline__ void store4(void* dst, float4 a, float sc) {
    union { __bf16 h[4]; uint2 u; } p;
    p.h[0] = (__bf16)(sc * a.x); p.h[1] = (__bf16)(sc * a.y);
    p.h[2] = (__bf16)(sc * a.z); p.h[3] = (__bf16)(sc * a.w);
    *reinterpret_cast<uint2*>(dst) = p.u;
}
__device__ __forceinline__ bf16x8 pack8(const float4 a, const float4 b) {
    bf16x8 r;
    r[0] = (__bf16)a.x; r[1] = (__bf16)a.y; r[2] = (__bf16)a.z; r[3] = (__bf16)a.w;
    r[4] = (__bf16)b.x; r[5] = (__bf16)b.y; r[6] = (__bf16)b.z; r[7] = (__bf16)b.w;
    return r;
}

// ================= launch 1: aux (swizzle + colsum + focal + graph) ============
__global__ __launch_bounds__(256) void aux_kernel(const float* __restrict__ feat,
                                                  const float* __restrict__ preds,
                                                  const float* __restrict__ targets,
                                                  const float* __restrict__ gfeat,
                                                  __bf16* __restrict__ ascr,
                                                  __bf16* __restrict__ bscr,
                                                  float* __restrict__ vpart,
                                                  float* __restrict__ spart,
                                                  float* __restrict__ f_part,
                                                  float* __restrict__ g_part) {
    __shared__ float fA[512], f1[512];
    __shared__ float sred[4][3];
    const int bx = blockIdx.x;
    const int tid = threadIdx.x;
    const int w = tid >> 6, lane = tid & 63;

    if (bx < NSWZ) {
        // ---- screen-panel swizzle: 128 rows/block, 2 threads/row ----
        const int rl = tid >> 1, h = tid & 1;
        const int grow = bx * 128 + rl;
        const int g = grow >> 4, m = grow & 15;
        const float4* f4 = reinterpret_cast<const float4*>(feat);
        const int o = grow * 32 + h * 3;
        const float4 a0 = f4[o], a1 = f4[o + 1], a2 = f4[o + 2];
        float s = ssq4(a0) + ssq4(a1) + ssq4(a2);
        const float sq24 = s + __shfl_xor(s, 1);     // both halves
        char* A = reinterpret_cast<char*>(ascr);
        char* B = reinterpret_cast<char*>(bscr);
        union { __bf16 x[8]; uint4 uu; } ug;
        #pragma unroll
        for (int i2 = 0; i2 < 8; ++i2) ug.x[i2] = (__bf16)0.f;
        if (h == 0) {                                // dims 0..11
            store8(A + uoff(g, 0, m), a0, a1, -2.f);
            store4(A + uoff(g, 1, m), a2, -2.f);
            store8(B + uoff(g, 0, m), a0, a1, 1.f);
            store4(B + uoff(g, 1, m), a2, 1.f);
            ug.x[0] = (__bf16)sq24; ug.x[1] = (__bf16)1.f;     // A aug
            *reinterpret_cast<uint4*>(A + uoff(g, 3, m)) = ug.uu;
        } else {                                     // dims 12..23
            store4(A + uoff(g, 1, m) + 8, a0, -2.f);
            store8(A + uoff(g, 2, m), a1, a2, -2.f);
            store4(B + uoff(g, 1, m) + 8, a0, 1.f);
            store8(B + uoff(g, 2, m), a1, a2, 1.f);
            ug.x[0] = (__bf16)1.f; ug.x[1] = (__bf16)sq24;     // B aug
            *reinterpret_cast<uint4*>(B + uoff(g, 3, m)) = ug.uu;
        }
    } else if (bx < NSWZ + NCOL) {
        // ---- per-class column sums + ssq/n per class (v1/v3-verified) ----
        const int b = bx - NSWZ;
        const float2* feat2 = reinterpret_cast<const float2*>(feat);
        float2 accA = {0.f, 0.f}, acc1 = {0.f, 0.f};
        float ssqA = 0.f, ssq1 = 0.f, n1 = 0.f;
        int r = b * 256 + w * 64;
        #pragma unroll 4
        for (int i = 0; i < 64; ++i, ++r) {
            const float2 v = feat2[r * 64 + lane];
            const float tr = targets[r];              // wave-uniform
            accA.x += v.x; accA.y += v.y;
            acc1.x += tr * v.x; acc1.y += tr * v.y;
            const float s2 = v.x * v.x + v.y * v.y;
            ssqA += s2; ssq1 += tr * s2; n1 += tr;    // n1 identical across lanes
        }
        fA[w * 128 + 2 * lane] = accA.x; fA[w * 128 + 2 * lane + 1] = accA.y;
        f1[w * 128 + 2 * lane] = acc1.x; f1[w * 128 + 2 * lane + 1] = acc1.y;
        #pragma unroll
        for (int off = 32; off > 0; off >>= 1) {
            ssqA += __shfl_down(ssqA, off);
            ssq1 += __shfl_down(ssq1, off);
        }
        if (lane == 0) { sred[w][0] = ssqA; sred[w][1] = ssq1; sred[w][2] = n1; }
        __syncthreads();
        if (tid < 128) {
            const int d = tid;
            const float c1 = f1[d] + f1[128 + d] + f1[256 + d] + f1[384 + d];
            const float ca = fA[d] + fA[128 + d] + fA[256 + d] + fA[384 + d];
            vpart[b * 256 + tid] = ca - c1;           // class 0
        } else {
            const int d = tid - 128;
            vpart[b * 256 + tid] = f1[d] + f1[128 + d] + f1[256 + d] + f1[384 + d];
        }
        if (tid == 0) {
            float4 s;
            s.x = sred[0][0] + sred[1][0] + sred[2][0] + sred[3][0];
            s.y = sred[0][1] + sred[1][1] + sred[2][1] + sred[3][1];
            s.z = sred[0][2] + sred[1][2] + sred[2][2] + sred[3][2];
            s.w = 0.f;
            *reinterpret_cast<float4*>(spart + b * 4) = s;
        }
    } else if (bx < NSWZ + NCOL + NFOC) {
        // ---- focal: 1024 elems/block ----
        const int b = bx - NSWZ - NCOL;
        float fv = 0.f;
        #pragma unroll
        for (int it = 0; it < 4; ++it) {
            const int i = b * 1024 + it * 256 + tid;
            const float p = preds[i], t = targets[i];
            const float bce = fmaxf(p, 0.f) - p * t + log1pf(expf(-fabsf(p)));
            const float pt = expf(-bce);
            const float om = 1.f - pt;
            fv += 0.25f * om * om * bce;
        }
        #pragma unroll
        for (int off = 32; off > 0; off >>= 1) fv += __shfl_down(fv, off);
        if (lane == 0) f_part[b * 4 + w] = fv;
    } else {
        // ---- graph: 128 rows/block, 4 independent shfl trees (v4-verified) ----
        const int b = bx - NSWZ - NCOL - NFOC;
        float ga = 0.f;
        for (int it = 0; it < 8; ++it) {
            const int rbase = b * 128 + w * 32 + it * 4;
            float s[4];
            #pragma unroll
            for (int q = 0; q < 4; ++q) {
                const int r = rbase + q;
                if (r < N_PTS - 1) {
                    const float2 a = *reinterpret_cast<const float2*>(gfeat + r * DIM + lane * 2);
                    const float2 bb = *reinterpret_cast<const float2*>(gfeat + (r + 1) * DIM + lane * 2);
                    const float dx = bb.x - a.x, dy = bb.y - a.y;
                    s[q] = dx * dx + dy * dy;
                } else s[q] = 0.f;
            }
            #pragma unroll
            for (int off = 32; off > 0; off >>= 1) {
                s[0] += __shfl_down(s[0], off);
                s[1] += __shfl_down(s[1], off);
                s[2] += __shfl_down(s[2], off);
                s[3] += __shfl_down(s[3], off);
            }
            if (lane == 0) {
                #pragma unroll
                for (int q = 0; q < 4; ++q)
                    if (rbase + q < N_PTS - 1) ga += sqrtf(s[q]);
            }
        }
        if (lane == 0) g_part[b * 4 + w] = ga;
    }
}

// ================= slow-path scan (unchanged, verified v1-v6) ==================
template<bool DIAG>
__device__ __forceinline__ float scan_slow(const f32x4 (&acc)[4][4],
                                           const f32x4 (&sqni)[4], const f32x4 (&ti4)[4],
                                           const float (&sqnj)[4], const float (&tj4)[4],
                                           int wm, int wn, int quad, int m15) {
    float lsum = 0.f;
    #pragma unroll
    for (int tm = 0; tm < 4; ++tm) {
        #pragma unroll
        for (int tn = 0; tn < 4; ++tn) {
            const int jl = wn * 64 + tn * 16 + m15;
            #pragma unroll
            for (int e = 0; e < 4; ++e) {
                const float sq = sqni[tm][e] + sqnj[tn] - 2.f * acc[tm][tn][e];
                bool excl = (ti4[tm][e] == tj4[tn]);
                if (DIAG) {
                    const int il = wm * 64 + tm * 16 + quad * 4 + e;
                    excl = excl || (jl <= il);
                }
                if (!excl && sq < 1.f) {
                    const float d = sqrtf(fmaxf(sq, 0.f));
                    const float m = 1.f - d;
                    lsum += 2.f * m * m;
                }
            }
        }
    }
    return lsum;
}

// ================= launch 2: pair (4 tiles/block, prestaged screen) ============
__global__ __launch_bounds__(256, 4) void pair_kernel(const float* __restrict__ feat,
                                                      const float* __restrict__ targets,
                                                      const __bf16* __restrict__ ascr,
                                                      const __bf16* __restrict__ bscr,
                                                      float* __restrict__ c_part) {
    const int tid = threadIdx.x;
    const int lane = tid & 63;
    const int w = tid >> 6;
    const int quad = lane >> 4, m15 = lane & 15;
    const int wm = w >> 1, wn = w & 1;
    const uint4* aS = reinterpret_cast<const uint4*>(ascr);
    const uint4* bS = reinterpret_cast<const uint4*>(bscr);
    float csum = 0.f;

    for (int t4 = 0; t4 < 4; ++t4) {
        const int u = blockIdx.x * 4 + t4;
        const int vv = 2079 - u;
        int k = (int)((sqrtf(8.f * (float)vv + 1.f) - 1.f) * 0.5f);
        while ((k + 1) * (k + 2) / 2 <= vv) ++k;
        while (k * (k + 1) / 2 > vv) --k;
        const int bi = 63 - k;
        const int bj = 63 - (vv - k * (k + 1) / 2);

        // ---- screen: coalesced L2 fragment reads + 16 MFMA; acc IS sq24 ----
        const int gA = bi * 8 + wm * 4, gB = bj * 8 + wn * 4;
        bf16x8 afs[4], bfs[4];
        #pragma unroll
        for (int t = 0; t < 4; ++t) {
            afs[t] = *reinterpret_cast<const bf16x8*>(aS + (gA + t) * 64 + quad * 16 + m15);
            bfs[t] = *reinterpret_cast<const bf16x8*>(bS + (gB + t) * 64 + quad * 16 + m15);
        }
        f32x4 acc[4][4];
        #pragma unroll
        for (int a = 0; a < 4; ++a)
            #pragma unroll
            for (int b = 0; b < 4; ++b) acc[a][b] = (f32x4){0.f, 0.f, 0.f, 0.f};
        #pragma unroll
        for (int tm = 0; tm < 4; ++tm)
            #pragma unroll
            for (int tn = 0; tn < 4; ++tn)
                acc[tm][tn] = __builtin_amdgcn_mfma_f32_16x16x32_bf16(
                    afs[tm], bfs[tn], acc[tm][tn], 0, 0, 0);

        float minv = 1e30f;
        #pragma unroll
        for (int tm = 0; tm < 4; ++tm)
            #pragma unroll
            for (int tn = 0; tn < 4; ++tn)
                #pragma unroll
                for (int e = 0; e < 4; ++e)
                    minv = fminf(minv, acc[tm][tn][e]);

        if (__any(minv < 2.f)) {
            // ---- exact slow path (v5 verbatim; diag tiles in practice) ----
            const int ibase = bi * 128 + wm * 64, jbase = bj * 128 + wn * 64;
            float qi = 0.f, qj = 0.f;
            {
                const float4* ri = reinterpret_cast<const float4*>(feat + (ibase + lane) * DIM);
                const float4* rj = reinterpret_cast<const float4*>(feat + (jbase + lane) * DIM);
                #pragma unroll 8
                for (int c2 = 0; c2 < 32; ++c2) {
                    const float4 x = ri[c2]; qi += x.x * x.x + x.y * x.y + x.z * x.z + x.w * x.w;
                    const float4 y = rj[c2]; qj += y.x * y.x + y.y * y.y + y.z * y.z + y.w * y.w;
                }
            }
            f32x4 sqni[4], ti4[4];
            float sqnj[4], tj4[4];
            #pragma unroll
            for (int tm = 0; tm < 4; ++tm) {
                #pragma unroll
                for (int e = 0; e < 4; ++e) sqni[tm][e] = __shfl(qi, tm * 16 + quad * 4 + e);
                ti4[tm] = *reinterpret_cast<const f32x4*>(targets + ibase + tm * 16 + quad * 4);
            }
            #pragma unroll
            for (int tn = 0; tn < 4; ++tn) {
                sqnj[tn] = __shfl(qj, tn * 16 + m15);
                tj4[tn] = targets[jbase + tn * 16 + m15];
            }
            #pragma unroll
            for (int a = 0; a < 4; ++a)
                #pragma unroll
                for (int b = 0; b < 4; ++b) acc[a][b] = (f32x4){0.f, 0.f, 0.f, 0.f};
            for (int ks = 0; ks < 4; ++ks) {
                bf16x8 af2[4], bf2[4];
                #pragma unroll
                for (int t = 0; t < 4; ++t) {
                    const float* pa = feat + (ibase + t * 16 + m15) * DIM + 8 * (quad + 4 * ks);
                    af2[t] = pack8(*reinterpret_cast<const float4*>(pa),
                                   *reinterpret_cast<const float4*>(pa + 4));
                    const float* pb = feat + (jbase + t * 16 + m15) * DIM + 8 * (quad + 4 * ks);
                    bf2[t] = pack8(*reinterpret_cast<const float4*>(pb),
                                   *reinterpret_cast<const float4*>(pb + 4));
                }
                #pragma unroll
                for (int tm = 0; tm < 4; ++tm)
                    #pragma unroll
                    for (int tn = 0; tn < 4; ++tn)
                        acc[tm][tn] = __builtin_amdgcn_mfma_f32_16x16x32_bf16(
                            af2[tm], bf2[tn], acc[tm][tn], 0, 0, 0);
            }
            csum += (bi == bj)
                ? scan_slow<true >(acc, sqni, ti4, sqnj, tj4, wm, wn, quad, m15)
                : scan_slow<false>(acc, sqni, ti4, sqnj, tj4, wm, wn, quad, m15);
        }
    }
    #pragma unroll
    for (int off = 32; off > 0; off >>= 1) csum += __shfl_down(csum, off);
    if (lane == 0) c_part[blockIdx.x * 4 + w] = csum;   // distinct slot per wave
}

// ================= launch 3: finalize (1 block, verified v1/v3) ================
__global__ __launch_bounds__(256) void finalize_kernel(const float* __restrict__ c_part,
                                                       const float* __restrict__ f_part,
                                                       const float* __restrict__ g_part,
                                                       const float* __restrict__ vpart,
                                                       const float* __restrict__ spart,
                                                       float* __restrict__ out) {
    __shared__ double sC[4], sF[4], sG[4], sV[4], sST[4], sS1[4], sN1[4];
    const int tid = threadIdx.x;
    const int w = tid >> 6, lane = tid & 63;

    double c = 0.0;
    for (int i = tid; i < NPAIRB * 4; i += 256) c += (double)c_part[i];
    double f = (tid < NFOC * 4) ? (double)f_part[tid] : 0.0;
    double g = (double)g_part[tid];                  // exactly 256 entries

    float V = 0.f;
    #pragma unroll 8
    for (int b2 = 0; b2 < NCOL; ++b2) V += vpart[b2 * 256 + tid];
    double vsq = (double)V * (double)V;              // tid<128: class0; else class1

    double st = 0.0, s1 = 0.0, n1 = 0.0;
    if (tid < NCOL) {
        const float4 s = *reinterpret_cast<const float4*>(spart + tid * 4);
        st = s.x; s1 = s.y; n1 = s.z;
    }
    #pragma unroll
    for (int off = 32; off > 0; off >>= 1) {
        c += __shfl_down(c, off);
        f += __shfl_down(f, off);
        g += __shfl_down(g, off);
        vsq += __shfl_down(vsq, off);
        st += __shfl_down(st, off);
        s1 += __shfl_down(s1, off);
        n1 += __shfl_down(n1, off);
    }
    if (lane == 0) {
        sC[w] = c; sF[w] = f; sG[w] = g; sV[w] = vsq;
        sST[w] = st; sS1[w] = s1; sN1[w] = n1;
    }
    __syncthreads();
    if (tid == 0) {
        const double cs = sC[0] + sC[1] + sC[2] + sC[3];
        const double fs = sF[0] + sF[1] + sF[2] + sF[3];
        const double gs = sG[0] + sG[1] + sG[2] + sG[3];
        const double v0sq = sV[0] + sV[1];           // waves 0,1 = class0
        const double v1sq = sV[2] + sV[3];
        const double stot = sST[0] + sST[1] + sST[2] + sST[3];
        const double s1s  = sS1[0] + sS1[1] + sS1[2] + sS1[3];
        const double n1s  = sN1[0] + sN1[1] + sN1[2] + sN1[3];
        const double n0s = (double)N_PTS - n1s;
        const double s0s = stot - s1s;
        const double same = 2.0 * (n0s * s0s - v0sq) + 2.0 * (n1s * s1s - v1sq);
        out[0] = (float)((cs + same) / ((double)N_PTS * (double)N_PTS)
                         + fs / (double)N_PTS
                         + 0.1 * (gs / (double)(N_PTS - 1)));
    }
}

extern "C" void kernel_launch(void* const* d_in, const int* in_sizes, int n_in,
                              void* d_out, int out_size, void* d_ws, size_t ws_size,
                              hipStream_t stream) {
    const float* preds    = (const float*)d_in[0];
    const float* targets  = (const float*)d_in[1];
    const float* features = (const float*)d_in[2];
    const float* gfeat    = (const float*)d_in[3];
    char* ws = (char*)d_ws;
    __bf16* ascr  = (__bf16*)(ws + ASCR_OFF);
    __bf16* bscr  = (__bf16*)(ws + BSCR_OFF);
    float* vpart  = (float*)(ws + VPART_OFF);
    float* spart  = (float*)(ws + SPART_OFF);
    float* c_part = (float*)(ws + CPART_OFF);
    float* f_part = (float*)(ws + FPART_OFF);
    float* g_part = (float*)(ws + GPART_OFF);
    float* out = (float*)d_out;

    aux_kernel<<<NAUX, 256, 0, stream>>>(features, preds, targets, gfeat,
                                         ascr, bscr, vpart, spart, f_part, g_part);
    pair_kernel<<<NPAIRB, 256, 0, stream>>>(features, targets, ascr, bscr, c_part);
    finalize_kernel<<<1, 256, 0, stream>>>(c_part, f_part, g_part, vpart, spart, out);
}

// Round 8
// 115.953 us; speedup vs baseline: 1.0762x; 1.0762x over previous
//
#include <hip/hip_runtime.h>
#include <hip/hip_bf16.h>

// HybridLoss: focal + contrastive + 0.1*graph_reg.  N=8192, D=128.
// v8: revert-to-best + validated trim.  Empirical ranking over 8 rounds:
// v1 (3 launches, prestaged coalesced screens, fbf coalesced slow path,
// 2080x256 pair blocks = max TLP) = 102.4 beats every deviation:
//   v2 atomics rendezvous (60us kernel), v3 scattered screens (43.5),
//   v4/v7 serial tiles (82 / 44.6), v5/v6 self-staging (107.7).
// v8 = v1's pair+finalize VERBATIM; aux keeps v1's outputs (fbf+ascr+bscr+
// sqn+colsums) in 168 WGs instead of 832: 64 swizzle blocks x 128 rows,
// 4 threads/row -- each thread owns 32 dims so sq24 (dims 0..23) is
// thread-local (no shuffles); row norm needs 2 shfl_xor.
//  - screen: augmented-row MFMA (A=[-2f0..23,sq24,1,0..], B=[f0..23,1,
//    sq24,0..]; acc IS sq24; wave-min >= 2 => skip), verified v1/v5/v6/v7.
//  - slow path: v1 verbatim (fbf coalesced gram + sqn loads).
//  - no atomics (v2 trap), no fences (round-3 trap), distinct-slot stores.

#define N_PTS 8192
#define DIM 128

typedef __bf16 bf16x8 __attribute__((ext_vector_type(8)));
typedef float f32x4 __attribute__((ext_vector_type(4)));

// aux grid: [0,64) swizzle+fbf, [64,96) colsum, [96,104) focal, [104,168) graph
#define NSWZ 64
#define NCOL 32
#define NFOC 8
#define NGRA 64
#define NAUX (NSWZ + NCOL + NFOC + NGRA)
#define NPAIR 2080

// workspace layout (bytes)
#define FBF_OFF   0                      // __bf16[8192*128] = 2MB (swizzled)
#define ASCR_OFF  2097152                // __bf16[8192*32] screen A
#define BSCR_OFF  2621440                // __bf16[8192*32] screen B
#define SQN_OFF   3145728                // float[8192]
#define VPART_OFF 3178496                // float[32][256] col sums (cls0 | cls1)
#define SPART_OFF 3211264                // float4[32]: {ssq_all, ssq_cls1, n1, 0}
#define CPART_OFF 3211776                // float[2080*4] pair per-wave partials
#define FPART_OFF 3245056                // float[8*4]    focal per-wave partials
#define GPART_OFF 3245184                // float[64*4]   graph per-wave partials

// screen unit(g,q,m) = ((g*4+q)*16+m)*16 bytes; row r=g*16+m, dims 8q..8q+7.
__device__ __forceinline__ int uoff(int g, int q, int m) {
    return ((g * 4 + q) * 16 + m) * 16;
}
// fbf uint4 index: g*256 + c*16 + m  (chunk c = dims 8c..8c+7)

__device__ __forceinline__ float ssq4(const float4 a) {
    return a.x * a.x + a.y * a.y + a.z * a.z + a.w * a.w;
}
__device__ __forceinline__ void store8(void* dst, float4 a, float4 b, float sc) {
    union { __bf16 h[8]; uint4 u; } p;
    p.h[0] = (__bf16)(sc * a.x); p.h[1] = (__bf16)(sc * a.y);
    p.h[2] = (__bf16)(sc * a.z); p.h[3] = (__bf16)(sc * a.w);
    p.h[4] = (__bf16)(sc * b.x); p.h[5] = (__bf16)(sc * b.y);
    p.h[6] = (__bf16)(sc * b.z); p.h[7] = (__bf16)(sc * b.w);
    *reinterpret_cast<uint4*>(dst) = p.u;
}
__device__ __forceinline__ uint4 pack8u(const float4 a, const float4 b) {
    union { __bf16 h[8]; uint4 u; } p;
    p.h[0] = (__bf16)a.x; p.h[1] = (__bf16)a.y;
    p.h[2] = (__bf16)a.z; p.h[3] = (__bf16)a.w;
    p.h[4] = (__bf16)b.x; p.h[5] = (__bf16)b.y;
    p.h[6] = (__bf16)b.z; p.h[7] = (__bf16)b.w;
    return p.u;
}

// ================= launch 1: aux (swizzle+fbf / colsum / focal / graph) ========
__global__ __launch_bounds__(256) void aux_kernel(const float* __restrict__ feat,
                                                  const float* __restrict__ preds,
                                                  const float* __restrict__ targets,
                                                  const float* __restrict__ gfeat,
                                                  __bf16* __restrict__ fbf,
                                                  __bf16* __restrict__ ascr,
                                                  __bf16* __restrict__ bscr,
                                                  float* __restrict__ sqn,
                                                  float* __restrict__ vpart,
                                                  float* __restrict__ spart,
                                                  float* __restrict__ f_part,
                                                  float* __restrict__ g_part) {
    __shared__ float fA[512], f1[512];
    __shared__ float sred[4][3];
    const int bx = blockIdx.x;
    const int tid = threadIdx.x;
    const int w = tid >> 6, lane = tid & 63;

    if (bx < NSWZ) {
        // ---- swizzle + fbf: 128 rows/block, 4 threads/row (32 dims each) ----
        const int r = bx * 128 + (tid >> 2), h = tid & 3;
        const int g = r >> 4, m = r & 15;
        const float4* f4 = reinterpret_cast<const float4*>(feat) + r * 32 + h * 8;
        float4 v[8];
        #pragma unroll
        for (int i = 0; i < 8; ++i) v[i] = f4[i];
        // fbf chunks 4h..4h+3 (coalesced-ish uint4 stores)
        uint4* fb = reinterpret_cast<uint4*>(fbf) + g * 256 + m;
        #pragma unroll
        for (int j = 0; j < 4; ++j)
            fb[(4 * h + j) * 16] = pack8u(v[2 * j], v[2 * j + 1]);
        // full row norm via 2 shfl_xor across the 4 row-threads
        float s = 0.f;
        #pragma unroll
        for (int i = 0; i < 8; ++i) s += ssq4(v[i]);
        s += __shfl_xor(s, 1); s += __shfl_xor(s, 2);
        if (h == 3) sqn[r] = s;
        if (h == 0) {
            // dims 0..23 all local: screen panels + augmented quad3
            const float sq24 = ssq4(v[0]) + ssq4(v[1]) + ssq4(v[2])
                             + ssq4(v[3]) + ssq4(v[4]) + ssq4(v[5]);
            char* A = reinterpret_cast<char*>(ascr);
            char* B = reinterpret_cast<char*>(bscr);
            store8(A + uoff(g, 0, m), v[0], v[1], -2.f);
            store8(A + uoff(g, 1, m), v[2], v[3], -2.f);
            store8(A + uoff(g, 2, m), v[4], v[5], -2.f);
            store8(B + uoff(g, 0, m), v[0], v[1], 1.f);
            store8(B + uoff(g, 1, m), v[2], v[3], 1.f);
            store8(B + uoff(g, 2, m), v[4], v[5], 1.f);
            union { __bf16 x[8]; uint4 uu; } ua, ub;
            #pragma unroll
            for (int i2 = 0; i2 < 8; ++i2) { ua.x[i2] = (__bf16)0.f; ub.x[i2] = (__bf16)0.f; }
            ua.x[0] = (__bf16)sq24; ua.x[1] = (__bf16)1.f;
            ub.x[0] = (__bf16)1.f;  ub.x[1] = (__bf16)sq24;
            *reinterpret_cast<uint4*>(A + uoff(g, 3, m)) = ua.uu;
            *reinterpret_cast<uint4*>(B + uoff(g, 3, m)) = ub.uu;
        }
    } else if (bx < NSWZ + NCOL) {
        // ---- per-class column sums + ssq/n per class (v1/v3/v7-verified) ----
        const int b = bx - NSWZ;
        const float2* feat2 = reinterpret_cast<const float2*>(feat);
        float2 accA = {0.f, 0.f}, acc1 = {0.f, 0.f};
        float ssqA = 0.f, ssq1 = 0.f, n1 = 0.f;
        int r = b * 256 + w * 64;
        #pragma unroll 4
        for (int i = 0; i < 64; ++i, ++r) {
            const float2 v = feat2[r * 64 + lane];
            const float tr = targets[r];              // wave-uniform
            accA.x += v.x; accA.y += v.y;
            acc1.x += tr * v.x; acc1.y += tr * v.y;
            const float s2 = v.x * v.x + v.y * v.y;
            ssqA += s2; ssq1 += tr * s2; n1 += tr;    // n1 identical across lanes
        }
        fA[w * 128 + 2 * lane] = accA.x; fA[w * 128 + 2 * lane + 1] = accA.y;
        f1[w * 128 + 2 * lane] = acc1.x; f1[w * 128 + 2 * lane + 1] = acc1.y;
        #pragma unroll
        for (int off = 32; off > 0; off >>= 1) {
            ssqA += __shfl_down(ssqA, off);
            ssq1 += __shfl_down(ssq1, off);
        }
        if (lane == 0) { sred[w][0] = ssqA; sred[w][1] = ssq1; sred[w][2] = n1; }
        __syncthreads();
        if (tid < 128) {
            const int d = tid;
            const float c1 = f1[d] + f1[128 + d] + f1[256 + d] + f1[384 + d];
            const float ca = fA[d] + fA[128 + d] + fA[256 + d] + fA[384 + d];
            vpart[b * 256 + tid] = ca - c1;           // class 0
        } else {
            const int d = tid - 128;
            vpart[b * 256 + tid] = f1[d] + f1[128 + d] + f1[256 + d] + f1[384 + d];
        }
        if (tid == 0) {
            float4 s;
            s.x = sred[0][0] + sred[1][0] + sred[2][0] + sred[3][0];
            s.y = sred[0][1] + sred[1][1] + sred[2][1] + sred[3][1];
            s.z = sred[0][2] + sred[1][2] + sred[2][2] + sred[3][2];
            s.w = 0.f;
            *reinterpret_cast<float4*>(spart + b * 4) = s;
        }
    } else if (bx < NSWZ + NCOL + NFOC) {
        // ---- focal: 1024 elems/block ----
        const int b = bx - NSWZ - NCOL;
        float fv = 0.f;
        #pragma unroll
        for (int it = 0; it < 4; ++it) {
            const int i = b * 1024 + it * 256 + tid;
            const float p = preds[i], t = targets[i];
            const float bce = fmaxf(p, 0.f) - p * t + log1pf(expf(-fabsf(p)));
            const float pt = expf(-bce);
            const float om = 1.f - pt;
            fv += 0.25f * om * om * bce;
        }
        #pragma unroll
        for (int off = 32; off > 0; off >>= 1) fv += __shfl_down(fv, off);
        if (lane == 0) f_part[b * 4 + w] = fv;
    } else {
        // ---- graph: 128 rows/block, 4 independent shfl trees (v4-verified) ----
        const int b = bx - NSWZ - NCOL - NFOC;
        float ga = 0.f;
        for (int it = 0; it < 8; ++it) {
            const int rbase = b * 128 + w * 32 + it * 4;
            float s[4];
            #pragma unroll
            for (int q = 0; q < 4; ++q) {
                const int r = rbase + q;
                if (r < N_PTS - 1) {
                    const float2 a = *reinterpret_cast<const float2*>(gfeat + r * DIM + lane * 2);
                    const float2 bb = *reinterpret_cast<const float2*>(gfeat + (r + 1) * DIM + lane * 2);
                    const float dx = bb.x - a.x, dy = bb.y - a.y;
                    s[q] = dx * dx + dy * dy;
                } else s[q] = 0.f;
            }
            #pragma unroll
            for (int off = 32; off > 0; off >>= 1) {
                s[0] += __shfl_down(s[0], off);
                s[1] += __shfl_down(s[1], off);
                s[2] += __shfl_down(s[2], off);
                s[3] += __shfl_down(s[3], off);
            }
            if (lane == 0) {
                #pragma unroll
                for (int q = 0; q < 4; ++q)
                    if (rbase + q < N_PTS - 1) ga += sqrtf(s[q]);
            }
        }
        if (lane == 0) g_part[b * 4 + w] = ga;
    }
}

// ================= slow-path scan (verified v1-v7) =============================
template<bool DIAG>
__device__ __forceinline__ float scan_slow(const f32x4 (&acc)[4][4],
                                           const f32x4 (&sqni)[4], const f32x4 (&ti4)[4],
                                           const float (&sqnj)[4], const float (&tj4)[4],
                                           int wm, int wn, int quad, int m15) {
    float lsum = 0.f;
    #pragma unroll
    for (int tm = 0; tm < 4; ++tm) {
        #pragma unroll
        for (int tn = 0; tn < 4; ++tn) {
            const int jl = wn * 64 + tn * 16 + m15;
            #pragma unroll
            for (int e = 0; e < 4; ++e) {
                const float sq = sqni[tm][e] + sqnj[tn] - 2.f * acc[tm][tn][e];
                bool excl = (ti4[tm][e] == tj4[tn]);
                if (DIAG) {
                    const int il = wm * 64 + tm * 16 + quad * 4 + e;
                    excl = excl || (jl <= il);
                }
                if (!excl && sq < 1.f) {
                    const float d = sqrtf(fmaxf(sq, 0.f));
                    const float m = 1.f - d;
                    lsum += 2.f * m * m;     // off-diag block or strict-upper: weight 2
                }
            }
        }
    }
    return lsum;
}

// ========== launch 2: pair (v1-verbatim: prestaged screen, fbf slow path) ======
__global__ __launch_bounds__(256, 4) void pair_kernel(const __bf16* __restrict__ fbf,
                                                      const __bf16* __restrict__ ascr,
                                                      const __bf16* __restrict__ bscr,
                                                      const float* __restrict__ sqn,
                                                      const float* __restrict__ targets,
                                                      float* __restrict__ c_part) {
    // decode upper-tri block index u -> (bi, bj), bi <= bj
    const int u = blockIdx.x;
    const int v = 2079 - u;
    int k = (int)((sqrtf(8.f * (float)v + 1.f) - 1.f) * 0.5f);
    while ((k + 1) * (k + 2) / 2 <= v) ++k;
    while (k * (k + 1) / 2 > v) --k;
    const int bi = 63 - k;
    const int bj = 63 - (v - k * (k + 1) / 2);

    const int tid = threadIdx.x;
    const int lane = tid & 63;
    const int wv = tid >> 6;
    const int quad = lane >> 4;
    const int m15 = lane & 15;
    const int wm = wv >> 1, wn = wv & 1;
    const int ibase = bi * 128, jbase = bj * 128;

    // ---- screen: one K=32 MFMA per 16x16 tile emits sq24 directly ----
    const uint4* aS = reinterpret_cast<const uint4*>(ascr);
    const uint4* bS = reinterpret_cast<const uint4*>(bscr);
    const int gA = bi * 8 + wm * 4, gB = bj * 8 + wn * 4;
    bf16x8 afs[4], bfs[4];
    #pragma unroll
    for (int t = 0; t < 4; ++t) {
        afs[t] = *reinterpret_cast<const bf16x8*>(aS + (gA + t) * 64 + quad * 16 + m15);
        bfs[t] = *reinterpret_cast<const bf16x8*>(bS + (gB + t) * 64 + quad * 16 + m15);
    }
    f32x4 acc[4][4];
    #pragma unroll
    for (int a = 0; a < 4; ++a)
        #pragma unroll
        for (int b = 0; b < 4; ++b) acc[a][b] = (f32x4){0.f, 0.f, 0.f, 0.f};
    #pragma unroll
    for (int tm = 0; tm < 4; ++tm)
        #pragma unroll
        for (int tn = 0; tn < 4; ++tn)
            acc[tm][tn] = __builtin_amdgcn_mfma_f32_16x16x32_bf16(
                afs[tm], bfs[tn], acc[tm][tn], 0, 0, 0);

    float minl = 1e30f;
    #pragma unroll
    for (int tm = 0; tm < 4; ++tm)
        #pragma unroll
        for (int tn = 0; tn < 4; ++tn)
            #pragma unroll
            for (int e = 0; e < 4; ++e)
                minl = fminf(minl, acc[tm][tn][e]);

    float lsum = 0.f;
    if (__any(minl < 2.f)) {
        // ---- exact slow path: full 128-dim Gram + label/triangle-aware scan ----
        f32x4 sqni[4], ti4[4];
        float sqnj[4], tj4[4];
        #pragma unroll
        for (int tm = 0; tm < 4; ++tm) {
            const int i0 = wm * 64 + tm * 16 + quad * 4;
            sqni[tm] = *reinterpret_cast<const f32x4*>(sqn + ibase + i0);
            ti4[tm]  = *reinterpret_cast<const f32x4*>(targets + ibase + i0);
        }
        #pragma unroll
        for (int tn = 0; tn < 4; ++tn) {
            const int jl = wn * 64 + tn * 16 + m15;
            sqnj[tn] = sqn[jbase + jl];
            tj4[tn]  = targets[jbase + jl];
        }
        #pragma unroll
        for (int a = 0; a < 4; ++a)
            #pragma unroll
            for (int b = 0; b < 4; ++b) acc[a][b] = (f32x4){0.f, 0.f, 0.f, 0.f};
        const uint4* fp = reinterpret_cast<const uint4*>(fbf);
        const uint4* base_a = fp + (bi * 8 + wm * 4) * 256 + quad * 16 + m15;
        const uint4* base_b = fp + (bj * 8 + wn * 4) * 256 + quad * 16 + m15;
        #pragma unroll
        for (int ks = 0; ks < 4; ++ks) {
            bf16x8 af[4], bfr[4];
            #pragma unroll
            for (int t = 0; t < 4; ++t) {
                af[t]  = *reinterpret_cast<const bf16x8*>(base_a + t * 256 + ks * 64);
                bfr[t] = *reinterpret_cast<const bf16x8*>(base_b + t * 256 + ks * 64);
            }
            #pragma unroll
            for (int tm = 0; tm < 4; ++tm)
                #pragma unroll
                for (int tn = 0; tn < 4; ++tn)
                    acc[tm][tn] = __builtin_amdgcn_mfma_f32_16x16x32_bf16(
                        af[tm], bfr[tn], acc[tm][tn], 0, 0, 0);
        }
        lsum = (bi == bj)
            ? scan_slow<true >(acc, sqni, ti4, sqnj, tj4, wm, wn, quad, m15)
            : scan_slow<false>(acc, sqni, ti4, sqnj, tj4, wm, wn, quad, m15);
        #pragma unroll
        for (int off = 32; off > 0; off >>= 1) lsum += __shfl_down(lsum, off);
    }
    if (lane == 0) c_part[u * 4 + wv] = lsum;
}

// ================= launch 3: finalize (1 block, verified v3/v7) ================
__global__ __launch_bounds__(256) void finalize_kernel(const float* __restrict__ c_part,
                                                       const float* __restrict__ f_part,
                                                       const float* __restrict__ g_part,
                                                       const float* __restrict__ vpart,
                                                       const float* __restrict__ spart,
                                                       float* __restrict__ out) {
    __shared__ double sC[4], sF[4], sG[4], sV[4], sST[4], sS1[4], sN1[4];
    const int tid = threadIdx.x;
    const int w = tid >> 6, lane = tid & 63;

    double c = 0.0;
    for (int i = tid; i < NPAIR * 4; i += 256) c += (double)c_part[i];
    double f = (tid < NFOC * 4) ? (double)f_part[tid] : 0.0;
    double g = (double)g_part[tid];                  // exactly 256 entries

    float V = 0.f;
    #pragma unroll 8
    for (int b2 = 0; b2 < NCOL; ++b2) V += vpart[b2 * 256 + tid];
    double vsq = (double)V * (double)V;              // tid<128: class0; else class1

    double st = 0.0, s1 = 0.0, n1 = 0.0;
    if (tid < NCOL) {
        const float4 s = *reinterpret_cast<const float4*>(spart + tid * 4);
        st = s.x; s1 = s.y; n1 = s.z;
    }
    #pragma unroll
    for (int off = 32; off > 0; off >>= 1) {
        c += __shfl_down(c, off);
        f += __shfl_down(f, off);
        g += __shfl_down(g, off);
        vsq += __shfl_down(vsq, off);
        st += __shfl_down(st, off);
        s1 += __shfl_down(s1, off);
        n1 += __shfl_down(n1, off);
    }
    if (lane == 0) {
        sC[w] = c; sF[w] = f; sG[w] = g; sV[w] = vsq;
        sST[w] = st; sS1[w] = s1; sN1[w] = n1;
    }
    __syncthreads();
    if (tid == 0) {
        const double cs = sC[0] + sC[1] + sC[2] + sC[3];
        const double fs = sF[0] + sF[1] + sF[2] + sF[3];
        const double gs = sG[0] + sG[1] + sG[2] + sG[3];
        const double v0sq = sV[0] + sV[1];           // waves 0,1 = class0
        const double v1sq = sV[2] + sV[3];
        const double stot = sST[0] + sST[1] + sST[2] + sST[3];
        const double s1s  = sS1[0] + sS1[1] + sS1[2] + sS1[3];
        const double n1s  = sN1[0] + sN1[1] + sN1[2] + sN1[3];
        const double n0s = (double)N_PTS - n1s;
        const double s0s = stot - s1s;
        const double same = 2.0 * (n0s * s0s - v0sq) + 2.0 * (n1s * s1s - v1sq);
        out[0] = (float)((cs + same) / ((double)N_PTS * (double)N_PTS)
                         + fs / (double)N_PTS
                         + 0.1 * (gs / (double)(N_PTS - 1)));
    }
}

extern "C" void kernel_launch(void* const* d_in, const int* in_sizes, int n_in,
                              void* d_out, int out_size, void* d_ws, size_t ws_size,
                              hipStream_t stream) {
    const float* preds    = (const float*)d_in[0];
    const float* targets  = (const float*)d_in[1];
    const float* features = (const float*)d_in[2];
    const float* gfeat    = (const float*)d_in[3];
    char* ws = (char*)d_ws;
    __bf16* fbf   = (__bf16*)(ws + FBF_OFF);
    __bf16* ascr  = (__bf16*)(ws + ASCR_OFF);
    __bf16* bscr  = (__bf16*)(ws + BSCR_OFF);
    float* sqn    = (float*)(ws + SQN_OFF);
    float* vpart  = (float*)(ws + VPART_OFF);
    float* spart  = (float*)(ws + SPART_OFF);
    float* c_part = (float*)(ws + CPART_OFF);
    float* f_part = (float*)(ws + FPART_OFF);
    float* g_part = (float*)(ws + GPART_OFF);
    float* out = (float*)d_out;

    aux_kernel<<<NAUX, 256, 0, stream>>>(features, preds, targets, gfeat,
                                         fbf, ascr, bscr, sqn,
                                         vpart, spart, f_part, g_part);
    pair_kernel<<<NPAIR, 256, 0, stream>>>(fbf, ascr, bscr, sqn, targets, c_part);
    finalize_kernel<<<1, 256, 0, stream>>>(c_part, f_part, g_part, vpart, spart, out);
}

// Round 9
// 105.265 us; speedup vs baseline: 1.1855x; 1.1015x over previous
//
#include <hip/hip_runtime.h>
#include <hip/hip_bf16.h>

// HybridLoss: focal + contrastive + 0.1*graph_reg.  N=8192, D=128.
// v9: round-0 v1 VERBATIM (aux 832 WG w/ coalesced LDS-staged swizzle, fbf
// slow path, finalize) + ONE change: pair = 528 x 1024-thread supertile
// blocks.  Each of 16 waves runs exactly one v1 pair-wave body (one quadrant
// wave-slot of a 256x256 supertile) -- fully parallel, no LDS, no new syncs,
// same prestaged screens.  WGs 2080->528 at identical wave count (~8.4k).
// Rationale: pair's ~30us tracks per-WG cost (~15ns x 2080), not its ~2us of
// real work; v4/v7 failed by SERIALIZING tiles per wave; v6 confounded the
// reduction with self-staging.  This isolates the WG-count variable.
//  - screen: augmented-row MFMA (A=[-2f0..23,sq24,1,0..], B=[f0..23,1,sq24,
//    0..]; acc IS sq24; wave-min >= 2 => skip) -- verified rounds 0,5,6,7,8.
//  - slow path: fbf coalesced full-gram + sqn (round-0-verified).
//  - no atomics (v2 trap), no fences (round-3 trap), distinct-slot stores.

#define N_PTS 8192
#define DIM 128

typedef __bf16 bf16x8 __attribute__((ext_vector_type(8)));
typedef float f32x4 __attribute__((ext_vector_type(4)));

// workspace layout (bytes)
#define FBF_OFF   0                            // __bf16[8192*128] = 2 MB (swizzled)
#define SQN_OFF   2097152                      // float[8192]
#define CPART_OFF 2129920                      // float[528*16] = 33792 B
#define FPART_OFF 2163712                      // float[32]
#define GPART_OFF 2163840                      // float[256]
#define VPART_OFF 2164864                      // float[32*256]
#define ASCR_OFF  2197632                      // __bf16[8192*32] = 512 KB (screen A)
#define BSCR_OFF  2721920                      // __bf16[8192*32] = 512 KB (screen B)

#define NSUPER 528                             // 32*33/2 supertiles of 256x256

// ======== aux: prep(bf16 swizzle + screen + sqn) / colsum / focal / graph ======
// grid: [0,512) prep, [512,544) colsum, [544,576) focal, [576,832) graph
// (round-0 verbatim -- measured good in the 102.4 run)
__global__ __launch_bounds__(256) void aux_kernel(const float* __restrict__ feat,
                                                  const float* __restrict__ preds,
                                                  const float* __restrict__ targets,
                                                  const float* __restrict__ gfeat,
                                                  __bf16* __restrict__ fbf,
                                                  __bf16* __restrict__ ascr,
                                                  __bf16* __restrict__ bscr,
                                                  float* __restrict__ sqn,
                                                  float* __restrict__ vpart,
                                                  float* __restrict__ f_part,
                                                  float* __restrict__ g_part) {
    __shared__ __align__(16) char smem[8192];
    const int bx = blockIdx.x;
    const int tid = threadIdx.x;
    const int w = tid >> 6;
    const int lane = tid & 63;

    if (bx < 512) {
        // ---- prep: 16 rows/block; full-F staging + screen copies + sqn ----
        // smem: [0,4K) F-chunks, [4K,5K) A-screen, [5K,6K) B-screen, [6K,7K) S[256]
        const int g = bx;
        const float4* feat4 = reinterpret_cast<const float4*>(feat);
        const float4 a = feat4[g * 512 + tid * 2];
        const float4 b = feat4[g * 512 + tid * 2 + 1];
        const int m = tid >> 4, c = tid & 15;     // row m, chunk c (dims 8c..8c+7)
        union { __bf16 h[8]; uint4 u; } pk;
        pk.h[0] = (__bf16)a.x; pk.h[1] = (__bf16)a.y;
        pk.h[2] = (__bf16)a.z; pk.h[3] = (__bf16)a.w;
        pk.h[4] = (__bf16)b.x; pk.h[5] = (__bf16)b.y;
        pk.h[6] = (__bf16)b.z; pk.h[7] = (__bf16)b.w;
        *reinterpret_cast<uint4*>(smem + c * 256 + m * 16) = pk.u;
        if (c < 3) {
            union { __bf16 h[8]; uint4 u; } pa;
            pa.h[0] = (__bf16)(-2.f * a.x); pa.h[1] = (__bf16)(-2.f * a.y);
            pa.h[2] = (__bf16)(-2.f * a.z); pa.h[3] = (__bf16)(-2.f * a.w);
            pa.h[4] = (__bf16)(-2.f * b.x); pa.h[5] = (__bf16)(-2.f * b.y);
            pa.h[6] = (__bf16)(-2.f * b.z); pa.h[7] = (__bf16)(-2.f * b.w);
            *reinterpret_cast<uint4*>(smem + 4096 + c * 256 + m * 16) = pa.u;
            *reinterpret_cast<uint4*>(smem + 5120 + c * 256 + m * 16) = pk.u;
        }
        const float s = a.x * a.x + a.y * a.y + a.z * a.z + a.w * a.w
                      + b.x * b.x + b.y * b.y + b.z * b.z + b.w * b.w;
        reinterpret_cast<float*>(smem + 6144)[m * 16 + c] = s;
        __syncthreads();
        if (c == 3) {
            const float* S = reinterpret_cast<const float*>(smem + 6144);
            const float sq24 = S[m * 16] + S[m * 16 + 1] + S[m * 16 + 2];
            union { __bf16 h[8]; uint4 u; } pa, pb;
            #pragma unroll
            for (int k = 0; k < 8; ++k) { pa.h[k] = (__bf16)0.f; pb.h[k] = (__bf16)0.f; }
            pa.h[0] = (__bf16)sq24; pa.h[1] = (__bf16)1.f;   // A: d24=sqn24, d25=1
            pb.h[0] = (__bf16)1.f;  pb.h[1] = (__bf16)sq24;  // B: d24=1, d25=sqn24
            *reinterpret_cast<uint4*>(smem + 4096 + 3 * 256 + m * 16) = pa.u;
            *reinterpret_cast<uint4*>(smem + 5120 + 3 * 256 + m * 16) = pb.u;
        }
        if (c == 0) {
            const float* S = reinterpret_cast<const float*>(smem + 6144);
            float t = 0.f;
            #pragma unroll
            for (int k = 0; k < 16; ++k) t += S[m * 16 + k];
            sqn[g * 16 + m] = t;
        }
        __syncthreads();
        reinterpret_cast<uint4*>(fbf)[g * 256 + tid] =
            *reinterpret_cast<const uint4*>(smem + tid * 16);
        if (tid < 64)
            reinterpret_cast<uint4*>(ascr)[g * 64 + tid] =
                *reinterpret_cast<const uint4*>(smem + 4096 + tid * 16);
        else if (tid < 128)
            reinterpret_cast<uint4*>(bscr)[g * 64 + (tid - 64)] =
                *reinterpret_cast<const uint4*>(smem + 5120 + (tid - 64) * 16);
    } else if (bx < 544) {
        // ---- per-class column sums: 256 rows per block, coalesced ----
        const int b = bx - 512;
        const float2* feat2 = reinterpret_cast<const float2*>(feat);
        float2 accA = {0.f, 0.f}, acc1 = {0.f, 0.f};
        int r = b * 256 + w * 64;
        #pragma unroll 4
        for (int i = 0; i < 64; ++i, ++r) {
            const float2 v = feat2[r * 64 + lane];
            const float tr = targets[r];
            accA.x += v.x; accA.y += v.y;
            acc1.x += tr * v.x; acc1.y += tr * v.y;
        }
        float* fA = reinterpret_cast<float*>(smem);          // [4][128]
        float* f1 = reinterpret_cast<float*>(smem + 2048);   // [4][128]
        fA[w * 128 + 2 * lane] = accA.x; fA[w * 128 + 2 * lane + 1] = accA.y;
        f1[w * 128 + 2 * lane] = acc1.x; f1[w * 128 + 2 * lane + 1] = acc1.y;
        __syncthreads();
        if (tid < 128) {
            const int d = tid;
            const float c1 = f1[d] + f1[128 + d] + f1[256 + d] + f1[384 + d];
            const float ca = fA[d] + fA[128 + d] + fA[256 + d] + fA[384 + d];
            vpart[b * 256 + tid] = ca - c1;                  // class 0
        } else {
            const int d = tid - 128;
            vpart[b * 256 + tid] = f1[d] + f1[128 + d] + f1[256 + d] + f1[384 + d];
        }
    } else if (bx < 576) {
        // ---- focal partials ----
        const int b = bx - 544;
        const int i = b * 256 + tid;
        const float p = preds[i], t = targets[i];
        const float bce = fmaxf(p, 0.f) - p * t + log1pf(expf(-fabsf(p)));
        const float pt = expf(-bce);
        const float om = 1.f - pt;
        float v = 0.25f * om * om * bce;
        #pragma unroll
        for (int off = 32; off > 0; off >>= 1) v += __shfl_down(v, off);
        float* red = reinterpret_cast<float*>(smem);
        if (lane == 0) red[w] = v;
        __syncthreads();
        if (tid == 0) f_part[b] = red[0] + red[1] + red[2] + red[3];
    } else {
        // ---- graph regularizer partials ----
        const int b = bx - 576;
        float acc = 0.f;
        #pragma unroll
        for (int it = 0; it < 8; ++it) {
            const int r = b * 4 + w + it * 1024;
            if (r < N_PTS - 1) {
                const float2 a = *reinterpret_cast<const float2*>(gfeat + r * DIM + lane * 2);
                const float2 bb = *reinterpret_cast<const float2*>(gfeat + (r + 1) * DIM + lane * 2);
                const float dx = bb.x - a.x, dy = bb.y - a.y;
                float s = dx * dx + dy * dy;
                #pragma unroll
                for (int off = 32; off > 0; off >>= 1) s += __shfl_down(s, off);
                if (lane == 0) acc += sqrtf(s);
            }
        }
        float* red = reinterpret_cast<float*>(smem);
        if (lane == 0) red[w] = acc;
        __syncthreads();
        if (tid == 0) g_part[b] = red[0] + red[1] + red[2] + red[3];
    }
}

// ================= slow-path scan (round-0 verbatim, verified) =================
template<bool DIAG>
__device__ __forceinline__ float scan_slow(const f32x4 (&acc)[4][4],
                                           const f32x4 (&sqni)[4], const f32x4 (&ti4)[4],
                                           const float (&sqnj)[4], const float (&tj4)[4],
                                           int wm, int wn, int quad, int m15) {
    float lsum = 0.f;
    #pragma unroll
    for (int tm = 0; tm < 4; ++tm) {
        #pragma unroll
        for (int tn = 0; tn < 4; ++tn) {
            const int jl = wn * 64 + tn * 16 + m15;
            #pragma unroll
            for (int e = 0; e < 4; ++e) {
                const float sq = sqni[tm][e] + sqnj[tn] - 2.f * acc[tm][tn][e];
                bool excl = (ti4[tm][e] == tj4[tn]);
                if (DIAG) {
                    const int il = wm * 64 + tm * 16 + quad * 4 + e;
                    excl = excl || (jl <= il);
                }
                if (!excl && sq < 1.f) {
                    const float d = sqrtf(fmaxf(sq, 0.f));
                    const float m = 1.f - d;
                    lsum += 2.f * m * m;     // off-diag block or strict-upper: weight 2
                }
            }
        }
    }
    return lsum;
}

// ========== pair: 528 x 1024-thread supertiles; wave = one v1 pair-wave ========
__global__ __launch_bounds__(1024, 4) void pair_kernel(const __bf16* __restrict__ fbf,
                                                       const __bf16* __restrict__ ascr,
                                                       const __bf16* __restrict__ bscr,
                                                       const float* __restrict__ sqn,
                                                       const float* __restrict__ targets,
                                                       float* __restrict__ c_part) {
    // decode upper-tri supertile index u -> (sbi, sbj), sbi <= sbj (32-grid)
    const int u = blockIdx.x;
    const int v = 527 - u;
    int k = (int)((sqrtf(8.f * (float)v + 1.f) - 1.f) * 0.5f);
    while ((k + 1) * (k + 2) / 2 <= v) ++k;
    while (k * (k + 1) / 2 > v) --k;
    const int sbi = 31 - k;
    const int sbj = 31 - (v - k * (k + 1) / 2);

    const int tid = threadIdx.x;
    const int lane = tid & 63;
    const int wv = tid >> 6;              // 0..15
    const int quad = lane >> 4;
    const int m15 = lane & 15;
    const int q = wv >> 2, wq = wv & 3;   // quadrant 0..3, wave-in-quadrant 0..3
    const int qm = q >> 1, qn = q & 1;
    const int bi = sbi * 2 + qm, bj = sbj * 2 + qn;
    const int wm = wq >> 1, wn = wq & 1;
    const bool active = (bi <= bj);       // skip mirror quadrant on diag supertiles

    float lsum = 0.f;
    if (active) {
        const int ibase = bi * 128, jbase = bj * 128;

        // ---- screen: one K=32 MFMA per 16x16 tile emits sq24 directly ----
        const uint4* aS = reinterpret_cast<const uint4*>(ascr);
        const uint4* bS = reinterpret_cast<const uint4*>(bscr);
        const int gA = bi * 8 + wm * 4, gB = bj * 8 + wn * 4;
        bf16x8 afs[4], bfs[4];
        #pragma unroll
        for (int t = 0; t < 4; ++t) {
            afs[t] = *reinterpret_cast<const bf16x8*>(aS + (gA + t) * 64 + quad * 16 + m15);
            bfs[t] = *reinterpret_cast<const bf16x8*>(bS + (gB + t) * 64 + quad * 16 + m15);
        }
        f32x4 acc[4][4];
        #pragma unroll
        for (int a = 0; a < 4; ++a)
            #pragma unroll
            for (int b = 0; b < 4; ++b) acc[a][b] = (f32x4){0.f, 0.f, 0.f, 0.f};
        #pragma unroll
        for (int tm = 0; tm < 4; ++tm)
            #pragma unroll
            for (int tn = 0; tn < 4; ++tn)
                acc[tm][tn] = __builtin_amdgcn_mfma_f32_16x16x32_bf16(
                    afs[tm], bfs[tn], acc[tm][tn], 0, 0, 0);

        float minl = 1e30f;
        #pragma unroll
        for (int tm = 0; tm < 4; ++tm)
            #pragma unroll
            for (int tn = 0; tn < 4; ++tn)
                #pragma unroll
                for (int e = 0; e < 4; ++e)
                    minl = fminf(minl, acc[tm][tn][e]);

        if (__any(minl < 2.f)) {
            // ---- exact slow path: full 128-dim Gram + label/triangle scan ----
            f32x4 sqni[4], ti4[4];
            float sqnj[4], tj4[4];
            #pragma unroll
            for (int tm = 0; tm < 4; ++tm) {
                const int i0 = wm * 64 + tm * 16 + quad * 4;
                sqni[tm] = *reinterpret_cast<const f32x4*>(sqn + ibase + i0);
                ti4[tm]  = *reinterpret_cast<const f32x4*>(targets + ibase + i0);
            }
            #pragma unroll
            for (int tn = 0; tn < 4; ++tn) {
                const int jl = wn * 64 + tn * 16 + m15;
                sqnj[tn] = sqn[jbase + jl];
                tj4[tn]  = targets[jbase + jl];
            }
            #pragma unroll
            for (int a = 0; a < 4; ++a)
                #pragma unroll
                for (int b = 0; b < 4; ++b) acc[a][b] = (f32x4){0.f, 0.f, 0.f, 0.f};
            const uint4* fp = reinterpret_cast<const uint4*>(fbf);
            const uint4* base_a = fp + (bi * 8 + wm * 4) * 256 + quad * 16 + m15;
            const uint4* base_b = fp + (bj * 8 + wn * 4) * 256 + quad * 16 + m15;
            #pragma unroll
            for (int ks = 0; ks < 4; ++ks) {
                bf16x8 af[4], bfr[4];
                #pragma unroll
                for (int t = 0; t < 4; ++t) {
                    af[t]  = *reinterpret_cast<const bf16x8*>(base_a + t * 256 + ks * 64);
                    bfr[t] = *reinterpret_cast<const bf16x8*>(base_b + t * 256 + ks * 64);
                }
                #pragma unroll
                for (int tm = 0; tm < 4; ++tm)
                    #pragma unroll
                    for (int tn = 0; tn < 4; ++tn)
                        acc[tm][tn] = __builtin_amdgcn_mfma_f32_16x16x32_bf16(
                            af[tm], bfr[tn], acc[tm][tn], 0, 0, 0);
            }
            lsum = (bi == bj)
                ? scan_slow<true >(acc, sqni, ti4, sqnj, tj4, wm, wn, quad, m15)
                : scan_slow<false>(acc, sqni, ti4, sqnj, tj4, wm, wn, quad, m15);
            #pragma unroll
            for (int off = 32; off > 0; off >>= 1) lsum += __shfl_down(lsum, off);
        }
    }
    if (lane == 0) c_part[u * 16 + wv] = lsum;   // distinct slot per wave
}

// ================= finalize (round-0 verbatim; c_part count updated) ===========
__global__ __launch_bounds__(256) void finalize_kernel(const float* __restrict__ c_part,
                                                       const float* __restrict__ f_part,
                                                       const float* __restrict__ g_part,
                                                       const float* __restrict__ vpart,
                                                       const float* __restrict__ sqn,
                                                       const float* __restrict__ targets,
                                                       float* __restrict__ out) {
    __shared__ float red[32];
    const int tid = threadIdx.x;
    const int w = tid >> 6, lane = tid & 63;

    float c = 0.f;
    for (int i = tid; i < NSUPER * 16; i += 256) c += c_part[i];
    float f = (tid < 32) ? f_part[tid] : 0.f;
    float g = g_part[tid];

    float V = 0.f;
    #pragma unroll 8
    for (int b = 0; b < 32; ++b) V += vpart[b * 256 + tid];
    float vsq = V * V;                 // tid<128: class 0; else class 1

    float stot = 0.f, s1 = 0.f, n1 = 0.f;
    for (int i = tid; i < N_PTS; i += 256) {
        const float s = sqn[i], t = targets[i];
        stot += s; s1 += t * s; n1 += t;
    }

    #pragma unroll
    for (int off = 32; off > 0; off >>= 1) {
        c += __shfl_down(c, off);
        f += __shfl_down(f, off);
        g += __shfl_down(g, off);
        vsq  += __shfl_down(vsq, off);
        stot += __shfl_down(stot, off);
        s1   += __shfl_down(s1, off);
        n1   += __shfl_down(n1, off);
    }
    if (lane == 0) {
        red[w] = c; red[4 + w] = f; red[8 + w] = g;
        red[12 + w] = vsq; red[16 + w] = stot; red[20 + w] = s1; red[24 + w] = n1;
    }
    __syncthreads();
    if (tid == 0) {
        const double cs = (double)red[0] + red[1] + red[2] + red[3];
        const double fs = (double)red[4] + red[5] + red[6] + red[7];
        const double gs = (double)red[8] + red[9] + red[10] + red[11];
        const double v0sq = (double)red[12] + red[13];   // waves 0,1 = class 0
        const double v1sq = (double)red[14] + red[15];
        const double st = (double)red[16] + red[17] + red[18] + red[19];
        const double s1s = (double)red[20] + red[21] + red[22] + red[23];
        const double n1s = (double)red[24] + red[25] + red[26] + red[27];
        const double n0s = (double)N_PTS - n1s;
        const double s0s = st - s1s;
        const double same = 2.0 * (n0s * s0s - v0sq) + 2.0 * (n1s * s1s - v1sq);
        out[0] = (float)((cs + same) / ((double)N_PTS * N_PTS)
                         + fs / N_PTS + 0.1 * (gs / (N_PTS - 1)));
    }
}

extern "C" void kernel_launch(void* const* d_in, const int* in_sizes, int n_in,
                              void* d_out, int out_size, void* d_ws, size_t ws_size,
                              hipStream_t stream) {
    const float* preds    = (const float*)d_in[0];
    const float* targets  = (const float*)d_in[1];
    const float* features = (const float*)d_in[2];
    const float* gfeat    = (const float*)d_in[3];
    char* ws = (char*)d_ws;
    __bf16* fbf   = (__bf16*)(ws + FBF_OFF);
    __bf16* ascr  = (__bf16*)(ws + ASCR_OFF);
    __bf16* bscr  = (__bf16*)(ws + BSCR_OFF);
    float* sqn    = (float*)(ws + SQN_OFF);
    float* c_part = (float*)(ws + CPART_OFF);
    float* f_part = (float*)(ws + FPART_OFF);
    float* g_part = (float*)(ws + GPART_OFF);
    float* vpart  = (float*)(ws + VPART_OFF);
    float* out = (float*)d_out;

    aux_kernel<<<832, 256, 0, stream>>>(features, preds, targets, gfeat,
                                        fbf, ascr, bscr, sqn, vpart, f_part, g_part);
    pair_kernel<<<NSUPER, 1024, 0, stream>>>(fbf, ascr, bscr, sqn, targets, c_part);
    finalize_kernel<<<1, 256, 0, stream>>>(c_part, f_part, g_part, vpart, sqn, targets, out);
}